// Round 9
// baseline (149.973 us; speedup 1.0000x reference)
//
#include <hip/hip_runtime.h>

typedef short    s16x8 __attribute__((ext_vector_type(8)));
typedef float    f32x4 __attribute__((ext_vector_type(4)));
typedef unsigned u32x4 __attribute__((ext_vector_type(4)));

#define BB 32
#define SS 2048
#define DD 64
#define QBLK 64
#define KVBLK 64
#define NQB (SS / QBLK)          // 32
#define NTILES (SS / KVBLK)      // 32

#define QSCALE (0.125f * 1.44269504088896340736f)

// LDS 40KB. K double-buffer @0/8192, V triple-buffer @16384+8192*i.
// Each: [64 rows][64 cols] bf16, 128B row stride, 16B-slot XOR (chunk^(row&7)).
// K rows = keys (d-major cols); V rows = d (k'-major cols, k' per PV B-frag map).
#define KBUF(i) ((i) * 8192)
#define VBUF(i) (16384 + (i) * 8192)

union U8 { u32x4 u; s16x8 s; };
struct SR { float v[2][8]; float4 k[2][2]; };

__device__ __forceinline__ unsigned pk2bf(float lo, float hi) {
  unsigned r;
  asm("v_cvt_pk_bf16_f32 %0, %1, %2" : "=v"(r) : "v"(lo), "v"(hi));
  return r;
}

// Drain LDS only (NOT vmem) then sync: prefetch loads stay in flight across barriers.
#define BARRIER() asm volatile("s_waitcnt lgkmcnt(0)\ns_barrier" ::: "memory")

__global__ __launch_bounds__(256, 4)
void attn_fwd(const float* __restrict__ Q, const float* __restrict__ Kg,
              const float* __restrict__ Vg, float* __restrict__ O) {
  __shared__ __align__(16) char smem[40960];
  const int tid  = threadIdx.x;
  const int w    = tid >> 6;          // 0..3
  const int lane = tid & 63;
  const int l15  = lane & 15;
  const int l16  = lane >> 4;

  // XCD-aware swizzle (bijective: 1024 = 8 * 128): 4 batches per XCD L2.
  const int bid0  = blockIdx.x;
  const int wid   = (bid0 & 7) * 128 + (bid0 >> 3);
  const int batch = wid >> 5;
  const int qb    = wid & 31;
  const size_t bstride = (size_t)batch * SS * DD;
  const int qrow0 = qb * QBLK + w * 16;

  // ---- Q B-frags (col=q=l15, k=d=dh*32+l16*8+j), pre-scaled ----
  s16x8 aq[2];
#pragma unroll
  for (int dh = 0; dh < 2; ++dh) {
    const float* qp = Q + bstride + (size_t)(qrow0 + l15) * DD + dh * 32 + l16 * 8;
    const float4 x = *(const float4*)qp;
    const float4 y = *(const float4*)(qp + 4);
    U8 u;
    u.u = (u32x4){ pk2bf(x.x * QSCALE, x.y * QSCALE), pk2bf(x.z * QSCALE, x.w * QSCALE),
                   pk2bf(y.x * QSCALE, y.y * QSCALE), pk2bf(y.z * QSCALE, y.w * QSCALE) };
    aq[dh] = u.s;
  }

  U8 ones;
  ones.u = (u32x4){0x3F803F80u, 0x3F803F80u, 0x3F803F80u, 0x3F803F80u};

  // O^T accumulators (lane: q=l15, d=dt*16+l16*4+r) + MFMA-computed row-sums.
  f32x4 oT[4];
#pragma unroll
  for (int dt = 0; dt < 4; ++dt) oT[dt] = (f32x4){0.f, 0.f, 0.f, 0.f};
  f32x4 osum = (f32x4){0.f, 0.f, 0.f, 0.f};
  float mrun = -1e30f;

  // ---- staging addresses (LDS offsets are buffer-relative) ----
  const float* gV = Vg + bstride + lane;
  const int vls0 = lane * 128 + (((2 * w + 0) ^ (lane & 7)) << 4);
  const int vls1 = lane * 128 + (((2 * w + 1) ^ (lane & 7)) << 4);
  const int kr  = tid >> 2;
  const int kc0 = (tid & 3) * 2;
  const float* gK = Kg + bstride + (size_t)kr * DD + kc0 * 8;
  const int kls0 = kr * 128 + (((kc0 + 0) ^ (kr & 7)) << 4);
  const int kls1 = kr * 128 + (((kc0 + 1) ^ (kr & 7)) << 4);

  SR A;
  f32x4 SA[4], SB[4];

  auto SL = [&](int t, SR& S) {
    const int kb = t * KVBLK;
#pragma unroll
    for (int h = 0; h < 2; ++h) {
      const int c = 2 * w + h;
      const float* g = gV + (size_t)(kb + (c >> 2) * 32 + (c & 3) * 4) * DD;
#pragma unroll
      for (int i = 0; i < 4; ++i) {
        S.v[h][i]     = g[(size_t)i * DD];
        S.v[h][4 + i] = g[(size_t)(16 + i) * DD];
      }
    }
#pragma unroll
    for (int h = 0; h < 2; ++h) {
      const float* g = gK + (size_t)kb * DD + h * 8;
      S.k[h][0] = *(const float4*)g;
      S.k[h][1] = *(const float4*)(g + 4);
    }
  };

  auto SW = [&](int koff, int voff, const SR& S) {
#pragma unroll
    for (int h = 0; h < 2; ++h) {
      u32x4 vv = (u32x4){ pk2bf(S.v[h][0], S.v[h][1]), pk2bf(S.v[h][2], S.v[h][3]),
                          pk2bf(S.v[h][4], S.v[h][5]), pk2bf(S.v[h][6], S.v[h][7]) };
      *(u32x4*)(smem + voff + (h ? vls1 : vls0)) = vv;
    }
#pragma unroll
    for (int h = 0; h < 2; ++h) {
      u32x4 kv = (u32x4){ pk2bf(S.k[h][0].x, S.k[h][0].y), pk2bf(S.k[h][0].z, S.k[h][0].w),
                          pk2bf(S.k[h][1].x, S.k[h][1].y), pk2bf(S.k[h][1].z, S.k[h][1].w) };
      *(u32x4*)(smem + koff + (h ? kls1 : kls0)) = kv;
    }
  };

  auto QK = [&](int koff, f32x4 (&s)[4]) {
    s16x8 bk[4][2];
#pragma unroll
    for (int kc = 0; kc < 4; ++kc)
#pragma unroll
      for (int dh = 0; dh < 2; ++dh)
        bk[kc][dh] = *(const s16x8*)(smem + koff + (kc * 16 + l15) * 128 +
                                     (((dh * 4 + l16) ^ (l15 & 7)) << 4));
    __builtin_amdgcn_s_setprio(1);
#pragma unroll
    for (int kc = 0; kc < 4; ++kc) {
      s[kc] = (f32x4){0.f, 0.f, 0.f, 0.f};
      s[kc] = __builtin_amdgcn_mfma_f32_16x16x32_bf16(bk[kc][0], aq[0], s[kc], 0, 0, 0);
      s[kc] = __builtin_amdgcn_mfma_f32_16x16x32_bf16(bk[kc][1], aq[1], s[kc], 0, 0, 0);
    }
    __builtin_amdgcn_s_setprio(0);
  };

  auto SMPV = [&](int voff, f32x4 (&s)[4]) {
    float m01 = fmaxf(fmaxf(fmaxf(s[0][0], s[0][1]), fmaxf(s[0][2], s[0][3])),
                      fmaxf(fmaxf(s[1][0], s[1][1]), fmaxf(s[1][2], s[1][3])));
    float m23 = fmaxf(fmaxf(fmaxf(s[2][0], s[2][1]), fmaxf(s[2][2], s[2][3])),
                      fmaxf(fmaxf(s[3][0], s[3][1]), fmaxf(s[3][2], s[3][3])));
    float mx = fmaxf(m01, m23);
    mx = fmaxf(mx, __shfl_xor(mx, 16));
    mx = fmaxf(mx, __shfl_xor(mx, 32));
    const int skip = __all(mx <= mrun + 8.0f);
    if (!skip) {
      const float mnew = fmaxf(mrun, mx);
      const float scl  = __builtin_amdgcn_exp2f(mrun - mnew);
      osum = osum * scl;
#pragma unroll
      for (int dt = 0; dt < 4; ++dt) oT[dt] = oT[dt] * scl;
      mrun = mnew;
    }
    // V^T A-frags issued early: ds_read latency overlaps the exp2/pack VALU
    s16x8 vt[4][2];
#pragma unroll
    for (int dt = 0; dt < 4; ++dt)
#pragma unroll
      for (int kc2 = 0; kc2 < 2; ++kc2)
        vt[dt][kc2] = *(const s16x8*)(smem + voff + (dt * 16 + l15) * 128 +
                                      (((kc2 * 4 + l16) ^ (l15 & 7)) << 4));
    float p[4][4];
#pragma unroll
    for (int kc = 0; kc < 4; ++kc)
#pragma unroll
      for (int r = 0; r < 4; ++r)
        p[kc][r] = __builtin_amdgcn_exp2f(s[kc][r] - mrun);
    U8 pb0, pb1;
    pb0.u = (u32x4){ pk2bf(p[0][0], p[0][1]), pk2bf(p[0][2], p[0][3]),
                     pk2bf(p[1][0], p[1][1]), pk2bf(p[1][2], p[1][3]) };
    pb1.u = (u32x4){ pk2bf(p[2][0], p[2][1]), pk2bf(p[2][2], p[2][3]),
                     pk2bf(p[3][0], p[3][1]), pk2bf(p[3][2], p[3][3]) };
    __builtin_amdgcn_s_setprio(1);
#pragma unroll
    for (int dt = 0; dt < 4; ++dt) {
      oT[dt] = __builtin_amdgcn_mfma_f32_16x16x32_bf16(vt[dt][0], pb0.s, oT[dt], 0, 0, 0);
      oT[dt] = __builtin_amdgcn_mfma_f32_16x16x32_bf16(vt[dt][1], pb1.s, oT[dt], 0, 0, 0);
    }
    // row-sum via ones-MFMA: every lane ends with sum over this tile's 64 keys
    osum = __builtin_amdgcn_mfma_f32_16x16x32_bf16(ones.s, pb0.s, osum, 0, 0, 0);
    osum = __builtin_amdgcn_mfma_f32_16x16x32_bf16(ones.s, pb1.s, osum, 0, 0, 0);
    __builtin_amdgcn_s_setprio(0);
  };

  // ---- prologue: stage tiles 0,1; QK(0) ----
  SL(0, A); SW(KBUF(0), VBUF(0), A);
  SL(1, A); SW(KBUF(1), VBUF(1), A);
  BARRIER();
  QK(KBUF(0), SA);
  BARRIER();

  // ---- main loop: 6-body unroll (periods 2 and 3 both divide 6 -> static offsets) ----
  for (int i = 0; i < 5; ++i) {
    const int t = 6 * i;
    SL(t + 2, A); QK(KBUF(1), SB); SMPV(VBUF(0), SA); SW(KBUF(0), VBUF(2), A); BARRIER();
    SL(t + 3, A); QK(KBUF(0), SA); SMPV(VBUF(1), SB); SW(KBUF(1), VBUF(0), A); BARRIER();
    SL(t + 4, A); QK(KBUF(1), SB); SMPV(VBUF(2), SA); SW(KBUF(0), VBUF(1), A); BARRIER();
    SL(t + 5, A); QK(KBUF(0), SA); SMPV(VBUF(0), SB); SW(KBUF(1), VBUF(2), A); BARRIER();
    SL(t + 6, A); QK(KBUF(1), SB); SMPV(VBUF(1), SA); SW(KBUF(0), VBUF(0), A); BARRIER();
    SL(t + 7, A); QK(KBUF(0), SA); SMPV(VBUF(2), SB); SW(KBUF(1), VBUF(1), A); BARRIER();
  }

  // ---- epilogue: tiles 30, 31 (staged; no further writes -> no barriers) ----
  QK(KBUF(1), SB);
  SMPV(VBUF(0), SA);
  SMPV(VBUF(1), SB);

  // ---- output: osum holds the full row-sum in every component ----
  const float inv = 1.0f / osum[0];
  float* ob = O + bstride + (size_t)(qrow0 + l15) * DD + l16 * 4;
#pragma unroll
  for (int dt = 0; dt < 4; ++dt)
#pragma unroll
    for (int r = 0; r < 4; ++r)
      ob[dt * 16 + r] = oT[dt][r] * inv;
}

extern "C" void kernel_launch(void* const* d_in, const int* in_sizes, int n_in,
                              void* d_out, int out_size, void* d_ws, size_t ws_size,
                              hipStream_t stream) {
  const float* Q = (const float*)d_in[0];
  const float* K = (const float*)d_in[1];
  const float* V = (const float*)d_in[2];
  float* Oo = (float*)d_out;
  dim3 grid(BB * NQB);   // 1024
  dim3 block(256);       // 4 waves
  hipLaunchKernelGGL(attn_fwd, grid, block, 0, stream, Q, K, V, Oo);
}

// Round 12
// 99.149 us; speedup vs baseline: 1.5126x; 1.5126x over previous
//
#include <hip/hip_runtime.h>

typedef short    s16x8 __attribute__((ext_vector_type(8)));
typedef float    f32x4 __attribute__((ext_vector_type(4)));
typedef unsigned u32x4 __attribute__((ext_vector_type(4)));

#define BB 32
#define SS 2048
#define DD 64
#define QBLK 128                 // 4 waves x 32 q-rows (2 subtiles of 16)
#define KVBLK 64
#define NQB (SS / QBLK)          // 16
#define NTILES (SS / KVBLK)      // 32

#define QSCALE (0.125f * 1.44269504088896340736f)

// LDS 32KB, buffers @0 and @16384. Per buffer: K [64 key][64 d] bf16 @+0 (8KB),
// Vt [64 d][64 k'] bf16 @+8192 (8KB). 128B row stride, 16B-slot XOR (chunk^(row&7)).
#define V_OFF 8192
#define BUFSZ 16384

union U8 { u32x4 u; s16x8 s; };
struct SR { float v[2][8]; float4 k[2][2]; };   // 32 floats per set

__device__ __forceinline__ unsigned pk2bf(float lo, float hi) {
  unsigned r;
  asm("v_cvt_pk_bf16_f32 %0, %1, %2" : "=v"(r) : "v"(lo), "v"(hi));
  return r;
}

// Drain LDS only (NOT vmem) then sync: prefetch loads stay in flight across barriers.
#define BARRIER() asm volatile("s_waitcnt lgkmcnt(0)\ns_barrier" ::: "memory")

__global__ __launch_bounds__(256, 2)
void attn_fwd(const float* __restrict__ Q, const float* __restrict__ Kg,
              const float* __restrict__ Vg, float* __restrict__ O) {
  __shared__ __align__(16) char smem[2 * BUFSZ];
  const int tid  = threadIdx.x;
  const int w    = tid >> 6;          // 0..3
  const int lane = tid & 63;
  const int l15  = lane & 15;
  const int l16  = lane >> 4;

  // XCD-aware swizzle (bijective: 512 = 8 * 64): 2 batches per XCD L2.
  const int bid0  = blockIdx.x;
  const int wid   = (bid0 & 7) * 64 + (bid0 >> 3);
  const int batch = wid >> 4;
  const int qb    = wid & 15;
  const size_t bstride = (size_t)batch * SS * DD;
  const int qrow0 = qb * QBLK + w * 32;

  // ---- Q B-frags: [qs][dh], q = qrow0 + qs*16 + l15, k=d=dh*32+l16*8+j ----
  s16x8 aq[2][2];
#pragma unroll
  for (int qs = 0; qs < 2; ++qs)
#pragma unroll
    for (int dh = 0; dh < 2; ++dh) {
      const float* qp = Q + bstride + (size_t)(qrow0 + qs * 16 + l15) * DD + dh * 32 + l16 * 8;
      const float4 x = *(const float4*)qp;
      const float4 y = *(const float4*)(qp + 4);
      U8 u;
      u.u = (u32x4){ pk2bf(x.x * QSCALE, x.y * QSCALE), pk2bf(x.z * QSCALE, x.w * QSCALE),
                     pk2bf(y.x * QSCALE, y.y * QSCALE), pk2bf(y.z * QSCALE, y.w * QSCALE) };
      aq[qs][dh] = u.s;
    }

  // O^T accumulators: [qs][dt], lane: q=l15, d=dt*16+l16*4+r.
  f32x4 oT[2][4];
#pragma unroll
  for (int qs = 0; qs < 2; ++qs)
#pragma unroll
    for (int dt = 0; dt < 4; ++dt) oT[qs][dt] = (f32x4){0.f, 0.f, 0.f, 0.f};
  float mrun[2] = {-1e30f, -1e30f};
  float lsum[2] = {0.f, 0.f};

  // ---- staging addresses (identical mapping to the verified round-8 stager) ----
  const float* gV = Vg + bstride + lane;
  const int vls0 = V_OFF + lane * 128 + (((2 * w + 0) ^ (lane & 7)) << 4);
  const int vls1 = V_OFF + lane * 128 + (((2 * w + 1) ^ (lane & 7)) << 4);
  const int kr  = tid >> 2;
  const int kc0 = (tid & 3) * 2;
  const float* gK = Kg + bstride + (size_t)kr * DD + kc0 * 8;
  const int kls0 = kr * 128 + (((kc0 + 0) ^ (kr & 7)) << 4);
  const int kls1 = kr * 128 + (((kc0 + 1) ^ (kr & 7)) << 4);

  SR A, C;

  auto SL = [&](int t, SR& S) {
    const int kb = t * KVBLK;
#pragma unroll
    for (int h = 0; h < 2; ++h) {
      const int c = 2 * w + h;
      const float* g = gV + (size_t)(kb + (c >> 2) * 32 + (c & 3) * 4) * DD;
#pragma unroll
      for (int i = 0; i < 4; ++i) {
        S.v[h][i]     = g[(size_t)i * DD];
        S.v[h][4 + i] = g[(size_t)(16 + i) * DD];
      }
    }
#pragma unroll
    for (int h = 0; h < 2; ++h) {
      const float* g = gK + (size_t)kb * DD + h * 8;
      S.k[h][0] = *(const float4*)g;
      S.k[h][1] = *(const float4*)(g + 4);
    }
  };

  auto SW = [&](int off, const SR& S) {
#pragma unroll
    for (int h = 0; h < 2; ++h) {
      u32x4 vv = (u32x4){ pk2bf(S.v[h][0], S.v[h][1]), pk2bf(S.v[h][2], S.v[h][3]),
                          pk2bf(S.v[h][4], S.v[h][5]), pk2bf(S.v[h][6], S.v[h][7]) };
      *(u32x4*)(smem + off + (h ? vls1 : vls0)) = vv;
    }
#pragma unroll
    for (int h = 0; h < 2; ++h) {
      u32x4 kv = (u32x4){ pk2bf(S.k[h][0].x, S.k[h][0].y), pk2bf(S.k[h][0].z, S.k[h][0].w),
                          pk2bf(S.k[h][1].x, S.k[h][1].y), pk2bf(S.k[h][1].z, S.k[h][1].w) };
      *(u32x4*)(smem + off + (h ? kls1 : kls0)) = kv;
    }
  };

  auto compute = [&](int off) {
    // K A-frags (shared by both q-subtiles): K[kc*16+l15][dh*32+l16*8+j]
    s16x8 bk[4][2];
#pragma unroll
    for (int kc = 0; kc < 4; ++kc)
#pragma unroll
      for (int dh = 0; dh < 2; ++dh)
        bk[kc][dh] = *(const s16x8*)(smem + off + (kc * 16 + l15) * 128 +
                                     (((dh * 4 + l16) ^ (l15 & 7)) << 4));
    // S^T: [qs][kc], lane q=l15, key = kc*16 + l16*4 + r
    f32x4 s[2][4];
    __builtin_amdgcn_s_setprio(1);
#pragma unroll
    for (int qs = 0; qs < 2; ++qs)
#pragma unroll
      for (int kc = 0; kc < 4; ++kc) {
        s[qs][kc] = (f32x4){0.f, 0.f, 0.f, 0.f};
        s[qs][kc] = __builtin_amdgcn_mfma_f32_16x16x32_bf16(bk[kc][0], aq[qs][0], s[qs][kc], 0, 0, 0);
        s[qs][kc] = __builtin_amdgcn_mfma_f32_16x16x32_bf16(bk[kc][1], aq[qs][1], s[qs][kc], 0, 0, 0);
      }
    __builtin_amdgcn_s_setprio(0);

    // V^T A-frags (shared): issued before softmax so ds latency hides under VALU
    s16x8 vt[4][2];
#pragma unroll
    for (int dt = 0; dt < 4; ++dt)
#pragma unroll
      for (int kc2 = 0; kc2 < 2; ++kc2)
        vt[dt][kc2] = *(const s16x8*)(smem + off + V_OFF + (dt * 16 + l15) * 128 +
                                      (((kc2 * 4 + l16) ^ (l15 & 7)) << 4));

#pragma unroll
    for (int qs = 0; qs < 2; ++qs) {
      float m01 = fmaxf(fmaxf(fmaxf(s[qs][0][0], s[qs][0][1]), fmaxf(s[qs][0][2], s[qs][0][3])),
                        fmaxf(fmaxf(s[qs][1][0], s[qs][1][1]), fmaxf(s[qs][1][2], s[qs][1][3])));
      float m23 = fmaxf(fmaxf(fmaxf(s[qs][2][0], s[qs][2][1]), fmaxf(s[qs][2][2], s[qs][2][3])),
                        fmaxf(fmaxf(s[qs][3][0], s[qs][3][1]), fmaxf(s[qs][3][2], s[qs][3][3])));
      float mx = fmaxf(m01, m23);
      mx = fmaxf(mx, __shfl_xor(mx, 16));
      mx = fmaxf(mx, __shfl_xor(mx, 32));
      // Unconditional online-softmax update (defer-max branch removed: bisect).
      const float mnew = fmaxf(mrun[qs], mx);
      const float scl  = __builtin_amdgcn_exp2f(mrun[qs] - mnew);
      mrun[qs] = mnew;
      lsum[qs] *= scl;
#pragma unroll
      for (int dt = 0; dt < 4; ++dt) oT[qs][dt] = oT[qs][dt] * scl;
      float p[4][4];
#pragma unroll
      for (int kc = 0; kc < 4; ++kc)
#pragma unroll
        for (int r = 0; r < 4; ++r)
          p[kc][r] = __builtin_amdgcn_exp2f(s[qs][kc][r] - mnew);
      lsum[qs] += ((((p[0][0] + p[0][1]) + (p[0][2] + p[0][3])) +
                    ((p[1][0] + p[1][1]) + (p[1][2] + p[1][3]))) +
                   (((p[2][0] + p[2][1]) + (p[2][2] + p[2][3])) +
                    ((p[3][0] + p[3][1]) + (p[3][2] + p[3][3]))));
      U8 pb0, pb1;   // B-frag: k' = kc2*32 + l16*8 + j  <->  key kc2*32+(j>>2)*16+l16*4+(j&3)
      pb0.u = (u32x4){ pk2bf(p[0][0], p[0][1]), pk2bf(p[0][2], p[0][3]),
                       pk2bf(p[1][0], p[1][1]), pk2bf(p[1][2], p[1][3]) };
      pb1.u = (u32x4){ pk2bf(p[2][0], p[2][1]), pk2bf(p[2][2], p[2][3]),
                       pk2bf(p[3][0], p[3][1]), pk2bf(p[3][2], p[3][3]) };
      __builtin_amdgcn_s_setprio(1);
#pragma unroll
      for (int dt = 0; dt < 4; ++dt) {
        oT[qs][dt] = __builtin_amdgcn_mfma_f32_16x16x32_bf16(vt[dt][0], pb0.s, oT[qs][dt], 0, 0, 0);
        oT[qs][dt] = __builtin_amdgcn_mfma_f32_16x16x32_bf16(vt[dt][1], pb1.s, oT[qs][dt], 0, 0, 0);
      }
      __builtin_amdgcn_s_setprio(0);
    }
  };

  // ---- round-8 proven schedule: SL(t+1) -> compute(t) -> SW(t+1) -> BARRIER ----
  SL(0, A);
  SW(0, A);
  BARRIER();
  for (int i = 0; i < NTILES / 2 - 1; ++i) {
    SL(2 * i + 1, C); compute(0);     SW(BUFSZ, C); BARRIER();
    SL(2 * i + 2, A); compute(BUFSZ); SW(0, A);     BARRIER();
  }
  SL(NTILES - 1, C);
  compute(0);            // tile 30
  SW(BUFSZ, C);
  BARRIER();
  compute(BUFSZ);        // tile 31

  // ---- epilogue ----
#pragma unroll
  for (int qs = 0; qs < 2; ++qs) {
    float lr = lsum[qs];
    lr += __shfl_xor(lr, 16);
    lr += __shfl_xor(lr, 32);
    const float inv = 1.0f / lr;
    float* ob = O + bstride + (size_t)(qrow0 + qs * 16 + l15) * DD + l16 * 4;
#pragma unroll
    for (int dt = 0; dt < 4; ++dt)
#pragma unroll
      for (int r = 0; r < 4; ++r)
        ob[dt * 16 + r] = oT[qs][dt][r] * inv;
  }
}

extern "C" void kernel_launch(void* const* d_in, const int* in_sizes, int n_in,
                              void* d_out, int out_size, void* d_ws, size_t ws_size,
                              hipStream_t stream) {
  const float* Q = (const float*)d_in[0];
  const float* K = (const float*)d_in[1];
  const float* V = (const float*)d_in[2];
  float* Oo = (float*)d_out;
  dim3 grid(BB * NQB);   // 512
  dim3 block(256);       // 4 waves
  hipLaunchKernelGGL(attn_fwd, grid, block, 0, stream, Q, K, V, Oo);
}

// Round 13
// 93.778 us; speedup vs baseline: 1.5992x; 1.0573x over previous
//
#include <hip/hip_runtime.h>

typedef short    s16x8 __attribute__((ext_vector_type(8)));
typedef float    f32x4 __attribute__((ext_vector_type(4)));
typedef unsigned u32x4 __attribute__((ext_vector_type(4)));

#define BB 32
#define SS 2048
#define DD 64
#define QBLK 128                 // 4 waves x 32 q-rows (2 subtiles of 16)
#define KVBLK 64
#define NQB (SS / QBLK)          // 16
#define NTILES (SS / KVBLK)      // 32

#define QSCALE (0.125f * 1.44269504088896340736f)

// LDS 32KB, buffers @0 and @16384. Per buffer: K [64 key][64 d] bf16 @+0 (8KB),
// Vt [64 d][64 k'] bf16 @+8192 (8KB). 128B row stride, 16B-slot XOR (chunk^(row&7)).
#define V_OFF 8192
#define BUFSZ 16384

union U8 { u32x4 u; s16x8 s; };
struct SR { float v[2][8]; float4 k[2][2]; };   // 32 floats per set

__device__ __forceinline__ unsigned pk2bf(float lo, float hi) {
  unsigned r;
  asm("v_cvt_pk_bf16_f32 %0, %1, %2" : "=v"(r) : "v"(lo), "v"(hi));
  return r;
}

// Drain LDS only (NOT vmem) then sync: prefetch loads stay in flight across barriers.
#define BARRIER() asm volatile("s_waitcnt lgkmcnt(0)\ns_barrier" ::: "memory")

__global__ __launch_bounds__(256, 1)   // grid-capped at 2 blocks/CU: grant full RF, avoid spills
void attn_fwd(const float* __restrict__ Q, const float* __restrict__ Kg,
              const float* __restrict__ Vg, float* __restrict__ O) {
  __shared__ __align__(16) char smem[2 * BUFSZ];
  const int tid  = threadIdx.x;
  const int w    = tid >> 6;          // 0..3
  const int lane = tid & 63;
  const int l15  = lane & 15;
  const int l16  = lane >> 4;

  // XCD-aware swizzle (bijective: 512 = 8 * 64): 2 batches per XCD L2.
  const int bid0  = blockIdx.x;
  const int wid   = (bid0 & 7) * 64 + (bid0 >> 3);
  const int batch = wid >> 4;
  const int qb    = wid & 15;
  const size_t bstride = (size_t)batch * SS * DD;
  const int qrow0 = qb * QBLK + w * 32;

  // ---- Q B-frags: [qs][dh], q = qrow0 + qs*16 + l15, k=d=dh*32+l16*8+j ----
  s16x8 aq[2][2];
#pragma unroll
  for (int qs = 0; qs < 2; ++qs)
#pragma unroll
    for (int dh = 0; dh < 2; ++dh) {
      const float* qp = Q + bstride + (size_t)(qrow0 + qs * 16 + l15) * DD + dh * 32 + l16 * 8;
      const float4 x = *(const float4*)qp;
      const float4 y = *(const float4*)(qp + 4);
      U8 u;
      u.u = (u32x4){ pk2bf(x.x * QSCALE, x.y * QSCALE), pk2bf(x.z * QSCALE, x.w * QSCALE),
                     pk2bf(y.x * QSCALE, y.y * QSCALE), pk2bf(y.z * QSCALE, y.w * QSCALE) };
      aq[qs][dh] = u.s;
    }

  // O^T accumulators: [qs][dt], lane: q=l15, d=dt*16+l16*4+r.
  f32x4 oT[2][4];
#pragma unroll
  for (int qs = 0; qs < 2; ++qs)
#pragma unroll
    for (int dt = 0; dt < 4; ++dt) oT[qs][dt] = (f32x4){0.f, 0.f, 0.f, 0.f};
  float mrun[2] = {-1e30f, -1e30f};
  float lsum[2] = {0.f, 0.f};

  // ---- staging addresses (identical mapping to the verified round-8 stager) ----
  const float* gV = Vg + bstride + lane;
  const int vls0 = V_OFF + lane * 128 + (((2 * w + 0) ^ (lane & 7)) << 4);
  const int vls1 = V_OFF + lane * 128 + (((2 * w + 1) ^ (lane & 7)) << 4);
  const int kr  = tid >> 2;
  const int kc0 = (tid & 3) * 2;
  const float* gK = Kg + bstride + (size_t)kr * DD + kc0 * 8;
  const int kls0 = kr * 128 + (((kc0 + 0) ^ (kr & 7)) << 4);
  const int kls1 = kr * 128 + (((kc0 + 1) ^ (kr & 7)) << 4);

  SR A, C;

  auto SL = [&](int t, SR& S) {
    const int kb = t * KVBLK;
#pragma unroll
    for (int h = 0; h < 2; ++h) {
      const int c = 2 * w + h;
      const float* g = gV + (size_t)(kb + (c >> 2) * 32 + (c & 3) * 4) * DD;
#pragma unroll
      for (int i = 0; i < 4; ++i) {
        S.v[h][i]     = g[(size_t)i * DD];
        S.v[h][4 + i] = g[(size_t)(16 + i) * DD];
      }
    }
#pragma unroll
    for (int h = 0; h < 2; ++h) {
      const float* g = gK + (size_t)kb * DD + h * 8;
      S.k[h][0] = *(const float4*)g;
      S.k[h][1] = *(const float4*)(g + 4);
    }
  };

  auto SW = [&](int off, const SR& S) {
#pragma unroll
    for (int h = 0; h < 2; ++h) {
      u32x4 vv = (u32x4){ pk2bf(S.v[h][0], S.v[h][1]), pk2bf(S.v[h][2], S.v[h][3]),
                          pk2bf(S.v[h][4], S.v[h][5]), pk2bf(S.v[h][6], S.v[h][7]) };
      *(u32x4*)(smem + off + (h ? vls1 : vls0)) = vv;
    }
#pragma unroll
    for (int h = 0; h < 2; ++h) {
      u32x4 kv = (u32x4){ pk2bf(S.k[h][0].x, S.k[h][0].y), pk2bf(S.k[h][0].z, S.k[h][0].w),
                          pk2bf(S.k[h][1].x, S.k[h][1].y), pk2bf(S.k[h][1].z, S.k[h][1].w) };
      *(u32x4*)(smem + off + (h ? kls1 : kls0)) = kv;
    }
  };

  auto compute = [&](int off) {
    // K A-frags (shared by both q-subtiles): K[kc*16+l15][dh*32+l16*8+j]
    s16x8 bk[4][2];
#pragma unroll
    for (int kc = 0; kc < 4; ++kc)
#pragma unroll
      for (int dh = 0; dh < 2; ++dh)
        bk[kc][dh] = *(const s16x8*)(smem + off + (kc * 16 + l15) * 128 +
                                     (((dh * 4 + l16) ^ (l15 & 7)) << 4));
    // S^T: [qs][kc], lane q=l15, key = kc*16 + l16*4 + r
    f32x4 s[2][4];
    __builtin_amdgcn_s_setprio(1);
#pragma unroll
    for (int qs = 0; qs < 2; ++qs)
#pragma unroll
      for (int kc = 0; kc < 4; ++kc) {
        s[qs][kc] = (f32x4){0.f, 0.f, 0.f, 0.f};
        s[qs][kc] = __builtin_amdgcn_mfma_f32_16x16x32_bf16(bk[kc][0], aq[qs][0], s[qs][kc], 0, 0, 0);
        s[qs][kc] = __builtin_amdgcn_mfma_f32_16x16x32_bf16(bk[kc][1], aq[qs][1], s[qs][kc], 0, 0, 0);
      }
    __builtin_amdgcn_s_setprio(0);

    // V^T A-frags (shared): issued before softmax so ds latency hides under VALU
    s16x8 vt[4][2];
#pragma unroll
    for (int dt = 0; dt < 4; ++dt)
#pragma unroll
      for (int kc2 = 0; kc2 < 2; ++kc2)
        vt[dt][kc2] = *(const s16x8*)(smem + off + V_OFF + (dt * 16 + l15) * 128 +
                                      (((kc2 * 4 + l16) ^ (l15 & 7)) << 4));

#pragma unroll
    for (int qs = 0; qs < 2; ++qs) {
      float m01 = fmaxf(fmaxf(fmaxf(s[qs][0][0], s[qs][0][1]), fmaxf(s[qs][0][2], s[qs][0][3])),
                        fmaxf(fmaxf(s[qs][1][0], s[qs][1][1]), fmaxf(s[qs][1][2], s[qs][1][3])));
      float m23 = fmaxf(fmaxf(fmaxf(s[qs][2][0], s[qs][2][1]), fmaxf(s[qs][2][2], s[qs][2][3])),
                        fmaxf(fmaxf(s[qs][3][0], s[qs][3][1]), fmaxf(s[qs][3][2], s[qs][3][3])));
      float mx = fmaxf(m01, m23);
      mx = fmaxf(mx, __shfl_xor(mx, 16));
      mx = fmaxf(mx, __shfl_xor(mx, 32));
      // Unconditional online-softmax update (defer-max branch removed: NaN source in r10/r11).
      const float mnew = fmaxf(mrun[qs], mx);
      const float scl  = __builtin_amdgcn_exp2f(mrun[qs] - mnew);
      mrun[qs] = mnew;
      lsum[qs] *= scl;
#pragma unroll
      for (int dt = 0; dt < 4; ++dt) oT[qs][dt] = oT[qs][dt] * scl;
      float p[4][4];
#pragma unroll
      for (int kc = 0; kc < 4; ++kc)
#pragma unroll
        for (int r = 0; r < 4; ++r)
          p[kc][r] = __builtin_amdgcn_exp2f(s[qs][kc][r] - mnew);
      lsum[qs] += ((((p[0][0] + p[0][1]) + (p[0][2] + p[0][3])) +
                    ((p[1][0] + p[1][1]) + (p[1][2] + p[1][3]))) +
                   (((p[2][0] + p[2][1]) + (p[2][2] + p[2][3])) +
                    ((p[3][0] + p[3][1]) + (p[3][2] + p[3][3]))));
      U8 pb0, pb1;   // B-frag: k' = kc2*32 + l16*8 + j  <->  key kc2*32+(j>>2)*16+l16*4+(j&3)
      pb0.u = (u32x4){ pk2bf(p[0][0], p[0][1]), pk2bf(p[0][2], p[0][3]),
                       pk2bf(p[1][0], p[1][1]), pk2bf(p[1][2], p[1][3]) };
      pb1.u = (u32x4){ pk2bf(p[2][0], p[2][1]), pk2bf(p[2][2], p[2][3]),
                       pk2bf(p[3][0], p[3][1]), pk2bf(p[3][2], p[3][3]) };
      __builtin_amdgcn_s_setprio(1);
#pragma unroll
      for (int dt = 0; dt < 4; ++dt) {
        oT[qs][dt] = __builtin_amdgcn_mfma_f32_16x16x32_bf16(vt[dt][0], pb0.s, oT[qs][dt], 0, 0, 0);
        oT[qs][dt] = __builtin_amdgcn_mfma_f32_16x16x32_bf16(vt[dt][1], pb1.s, oT[qs][dt], 0, 0, 0);
      }
      __builtin_amdgcn_s_setprio(0);
    }
  };

  // ---- round-8 proven schedule: SL(t+1) -> compute(t) -> SW(t+1) -> BARRIER ----
  SL(0, A);
  SW(0, A);
  BARRIER();
  for (int i = 0; i < NTILES / 2 - 1; ++i) {
    SL(2 * i + 1, C); compute(0);     SW(BUFSZ, C); BARRIER();
    SL(2 * i + 2, A); compute(BUFSZ); SW(0, A);     BARRIER();
  }
  SL(NTILES - 1, C);
  compute(0);            // tile 30
  SW(BUFSZ, C);
  BARRIER();
  compute(BUFSZ);        // tile 31

  // ---- epilogue ----
#pragma unroll
  for (int qs = 0; qs < 2; ++qs) {
    float lr = lsum[qs];
    lr += __shfl_xor(lr, 16);
    lr += __shfl_xor(lr, 32);
    const float inv = 1.0f / lr;
    float* ob = O + bstride + (size_t)(qrow0 + qs * 16 + l15) * DD + l16 * 4;
#pragma unroll
    for (int dt = 0; dt < 4; ++dt)
#pragma unroll
      for (int r = 0; r < 4; ++r)
        ob[dt * 16 + r] = oT[qs][dt][r] * inv;
  }
}

extern "C" void kernel_launch(void* const* d_in, const int* in_sizes, int n_in,
                              void* d_out, int out_size, void* d_ws, size_t ws_size,
                              hipStream_t stream) {
  const float* Q = (const float*)d_in[0];
  const float* K = (const float*)d_in[1];
  const float* V = (const float*)d_in[2];
  float* Oo = (float*)d_out;
  dim3 grid(BB * NQB);   // 512
  dim3 block(256);       // 4 waves
  hipLaunchKernelGGL(attn_fwd, grid, block, 0, stream, Q, K, V, Oo);
}

// Round 14
// 89.826 us; speedup vs baseline: 1.6696x; 1.0440x over previous
//
#include <hip/hip_runtime.h>

typedef short    s16x8 __attribute__((ext_vector_type(8)));
typedef float    f32x4 __attribute__((ext_vector_type(4)));
typedef unsigned u32x4 __attribute__((ext_vector_type(4)));

#define BB 32
#define SS 2048
#define DD 64
#define QBLK 64
#define KVBLK 64
#define NQB (SS / QBLK)          // 32

#define QSCALE (0.125f * 1.44269504088896340736f)

#define V_OFF 8192
#define BUFSZ 16384

union U8 { u32x4 u; s16x8 s; };
struct SR { float v[2][8]; float4 k[2][2]; };

__device__ __forceinline__ unsigned pk2bf(float lo, float hi) {
  unsigned r;
  asm("v_cvt_pk_bf16_f32 %0, %1, %2" : "=v"(r) : "v"(lo), "v"(hi));
  return r;
}

#define BARRIER() asm volatile("s_waitcnt lgkmcnt(0)\ns_barrier" ::: "memory")

// NT = KV tiles per block. PARTIAL: store (O_unnorm, m, l) to workspace (split-K).
template<int NT, bool PARTIAL>
__global__ __launch_bounds__(256, 4)
void attn_fwd(const float* __restrict__ Q, const float* __restrict__ Kg,
              const float* __restrict__ Vg, float* __restrict__ O,
              float* __restrict__ Op, float* __restrict__ Ml) {
  __shared__ __align__(16) char smem[2 * BUFSZ];
  const int tid  = threadIdx.x;
  const int w    = tid >> 6;
  const int lane = tid & 63;
  const int l15  = lane & 15;
  const int l16  = lane >> 4;

  // XCD swizzle, batch-major: each XCD L2 holds 4 full batches of K/V (4MB).
  const int bid0 = blockIdx.x;
  int batch, qb, kh;
  if (PARTIAL) {
    const int wid = (bid0 & 7) * 256 + (bid0 >> 3);   // 2048 = 8*256, bijective
    batch = wid >> 6; kh = (wid >> 5) & 1; qb = wid & 31;
  } else {
    const int wid = (bid0 & 7) * 128 + (bid0 >> 3);   // 1024 = 8*128
    batch = wid >> 5; kh = 0; qb = wid & 31;
  }
  const size_t bstride = (size_t)batch * SS * DD;
  const int qrow0 = qb * QBLK + w * 16;
  const int kb0   = kh * (NT * KVBLK);

  s16x8 aq[2];
#pragma unroll
  for (int dh = 0; dh < 2; ++dh) {
    const float* qp = Q + bstride + (size_t)(qrow0 + l15) * DD + dh * 32 + l16 * 8;
    const float4 x = *(const float4*)qp;
    const float4 y = *(const float4*)(qp + 4);
    U8 u;
    u.u = (u32x4){ pk2bf(x.x * QSCALE, x.y * QSCALE), pk2bf(x.z * QSCALE, x.w * QSCALE),
                   pk2bf(y.x * QSCALE, y.y * QSCALE), pk2bf(y.z * QSCALE, y.w * QSCALE) };
    aq[dh] = u.s;
  }

  f32x4 oT[4];
#pragma unroll
  for (int dt = 0; dt < 4; ++dt) oT[dt] = (f32x4){0.f, 0.f, 0.f, 0.f};
  float mrun = -1e30f;
  float lsum = 0.f;

  const float* gV = Vg + bstride + lane;
  const int vls0 = V_OFF + lane * 128 + (((2 * w + 0) ^ (lane & 7)) << 4);
  const int vls1 = V_OFF + lane * 128 + (((2 * w + 1) ^ (lane & 7)) << 4);
  const int kr  = tid >> 2;
  const int kc0 = (tid & 3) * 2;
  const float* gK = Kg + bstride + (size_t)kr * DD + kc0 * 8;
  const int kls0 = kr * 128 + (((kc0 + 0) ^ (kr & 7)) << 4);
  const int kls1 = kr * 128 + (((kc0 + 1) ^ (kr & 7)) << 4);

  SR A, C;

  auto SL = [&](int t, SR& S) {
    const int kb = kb0 + t * KVBLK;
#pragma unroll
    for (int h = 0; h < 2; ++h) {
      const int c = 2 * w + h;
      const float* g = gV + (size_t)(kb + (c >> 2) * 32 + (c & 3) * 4) * DD;
#pragma unroll
      for (int i = 0; i < 4; ++i) {
        S.v[h][i]     = g[(size_t)i * DD];
        S.v[h][4 + i] = g[(size_t)(16 + i) * DD];
      }
    }
#pragma unroll
    for (int h = 0; h < 2; ++h) {
      const float* g = gK + (size_t)kb * DD + h * 8;
      S.k[h][0] = *(const float4*)g;
      S.k[h][1] = *(const float4*)(g + 4);
    }
  };

  auto SW = [&](int off, const SR& S) {
#pragma unroll
    for (int h = 0; h < 2; ++h) {
      u32x4 vv = (u32x4){ pk2bf(S.v[h][0], S.v[h][1]), pk2bf(S.v[h][2], S.v[h][3]),
                          pk2bf(S.v[h][4], S.v[h][5]), pk2bf(S.v[h][6], S.v[h][7]) };
      *(u32x4*)(smem + off + (h ? vls1 : vls0)) = vv;
    }
#pragma unroll
    for (int h = 0; h < 2; ++h) {
      u32x4 kv = (u32x4){ pk2bf(S.k[h][0].x, S.k[h][0].y), pk2bf(S.k[h][0].z, S.k[h][0].w),
                          pk2bf(S.k[h][1].x, S.k[h][1].y), pk2bf(S.k[h][1].z, S.k[h][1].w) };
      *(u32x4*)(smem + off + (h ? kls1 : kls0)) = kv;
    }
  };

  auto compute = [&](int off) {
    s16x8 bk[4][2];
#pragma unroll
    for (int kc = 0; kc < 4; ++kc)
#pragma unroll
      for (int dh = 0; dh < 2; ++dh)
        bk[kc][dh] = *(const s16x8*)(smem + off + (kc * 16 + l15) * 128 +
                                     (((dh * 4 + l16) ^ (l15 & 7)) << 4));
    f32x4 s[4];
    __builtin_amdgcn_s_setprio(1);
#pragma unroll
    for (int kc = 0; kc < 4; ++kc) {
      s[kc] = (f32x4){0.f, 0.f, 0.f, 0.f};
      s[kc] = __builtin_amdgcn_mfma_f32_16x16x32_bf16(bk[kc][0], aq[0], s[kc], 0, 0, 0);
      s[kc] = __builtin_amdgcn_mfma_f32_16x16x32_bf16(bk[kc][1], aq[1], s[kc], 0, 0, 0);
    }
    __builtin_amdgcn_s_setprio(0);

    float m01 = fmaxf(fmaxf(fmaxf(s[0][0], s[0][1]), fmaxf(s[0][2], s[0][3])),
                      fmaxf(fmaxf(s[1][0], s[1][1]), fmaxf(s[1][2], s[1][3])));
    float m23 = fmaxf(fmaxf(fmaxf(s[2][0], s[2][1]), fmaxf(s[2][2], s[2][3])),
                      fmaxf(fmaxf(s[3][0], s[3][1]), fmaxf(s[3][2], s[3][3])));
    float mx = fmaxf(m01, m23);
    mx = fmaxf(mx, __shfl_xor(mx, 16));
    mx = fmaxf(mx, __shfl_xor(mx, 32));
    const int skip = __all(mx <= mrun + 8.0f);
    if (!skip) {
      const float mnew = fmaxf(mrun, mx);
      const float scl  = __builtin_amdgcn_exp2f(mrun - mnew);
      lsum *= scl;
#pragma unroll
      for (int dt = 0; dt < 4; ++dt) oT[dt] = oT[dt] * scl;
      mrun = mnew;
    }
    s16x8 vt[4][2];
#pragma unroll
    for (int dt = 0; dt < 4; ++dt)
#pragma unroll
      for (int kc2 = 0; kc2 < 2; ++kc2)
        vt[dt][kc2] = *(const s16x8*)(smem + off + V_OFF + (dt * 16 + l15) * 128 +
                                      (((kc2 * 4 + l16) ^ (l15 & 7)) << 4));
    float p[4][4];
#pragma unroll
    for (int kc = 0; kc < 4; ++kc)
#pragma unroll
      for (int r = 0; r < 4; ++r)
        p[kc][r] = __builtin_amdgcn_exp2f(s[kc][r] - mrun);
    lsum += ((((p[0][0] + p[0][1]) + (p[0][2] + p[0][3])) +
              ((p[1][0] + p[1][1]) + (p[1][2] + p[1][3]))) +
             (((p[2][0] + p[2][1]) + (p[2][2] + p[2][3])) +
              ((p[3][0] + p[3][1]) + (p[3][2] + p[3][3]))));
    U8 pb0, pb1;
    pb0.u = (u32x4){ pk2bf(p[0][0], p[0][1]), pk2bf(p[0][2], p[0][3]),
                     pk2bf(p[1][0], p[1][1]), pk2bf(p[1][2], p[1][3]) };
    pb1.u = (u32x4){ pk2bf(p[2][0], p[2][1]), pk2bf(p[2][2], p[2][3]),
                     pk2bf(p[3][0], p[3][1]), pk2bf(p[3][2], p[3][3]) };
    __builtin_amdgcn_s_setprio(1);
#pragma unroll
    for (int dt = 0; dt < 4; ++dt) {
      oT[dt] = __builtin_amdgcn_mfma_f32_16x16x32_bf16(vt[dt][0], pb0.s, oT[dt], 0, 0, 0);
      oT[dt] = __builtin_amdgcn_mfma_f32_16x16x32_bf16(vt[dt][1], pb1.s, oT[dt], 0, 0, 0);
    }
    __builtin_amdgcn_s_setprio(0);
  };

  SL(0, A);
  SW(0, A);
  BARRIER();
  for (int i = 0; i < NT / 2 - 1; ++i) {
    SL(2 * i + 1, C); compute(0);     SW(BUFSZ, C); BARRIER();
    SL(2 * i + 2, A); compute(BUFSZ); SW(0, A);     BARRIER();
  }
  SL(NT - 1, C);
  compute(0);
  SW(BUFSZ, C);
  BARRIER();
  compute(BUFSZ);

  float lr = lsum;
  lr += __shfl_xor(lr, 16);
  lr += __shfl_xor(lr, 32);

  if (PARTIAL) {
    const size_t row = (size_t)kh * (BB * SS) + (size_t)batch * SS + qrow0 + l15;
    float* ob = Op + row * DD + l16 * 4;
#pragma unroll
    for (int dt = 0; dt < 4; ++dt)
#pragma unroll
      for (int r = 0; r < 4; ++r)
        ob[dt * 16 + r] = oT[dt][r];
    if (l16 == 0) {
      Ml[row * 2 + 0] = mrun;
      Ml[row * 2 + 1] = lr;
    }
  } else {
    const float inv = 1.0f / lr;
    float* ob = O + bstride + (size_t)(qrow0 + l15) * DD + l16 * 4;
#pragma unroll
    for (int dt = 0; dt < 4; ++dt)
#pragma unroll
      for (int r = 0; r < 4; ++r)
        ob[dt * 16 + r] = oT[dt][r] * inv;
  }
}

// Deterministic split-K combine: O = (w0*O0 + w1*O1) / (w0*l0 + w1*l1).
__global__ __launch_bounds__(256, 8)
void combine(const float* __restrict__ Op, const float* __restrict__ Ml,
             float* __restrict__ O) {
  const int wv   = threadIdx.x >> 6;
  const int lane = threadIdx.x & 63;
  const int c    = lane & 15;        // d-chunk (float4)
  const int r4   = lane >> 4;        // row within 4-group
  const size_t half = (size_t)BB * SS;   // 65536 rows per split half
#pragma unroll
  for (int pass = 0; pass < 4; ++pass) {
    const size_t row = (size_t)blockIdx.x * 64 + wv * 16 + pass * 4 + r4;
    const float m0 = Ml[row * 2], l0 = Ml[row * 2 + 1];
    const float m1 = Ml[(half + row) * 2], l1 = Ml[(half + row) * 2 + 1];
    const float M  = fmaxf(m0, m1);
    const float w0 = __builtin_amdgcn_exp2f(m0 - M);
    const float w1 = __builtin_amdgcn_exp2f(m1 - M);
    const float inv = 1.0f / (w0 * l0 + w1 * l1);
    const float4 o0 = *(const float4*)(Op + row * DD + c * 4);
    const float4 o1 = *(const float4*)(Op + (half + row) * DD + c * 4);
    float4 o;
    o.x = (w0 * o0.x + w1 * o1.x) * inv;
    o.y = (w0 * o0.y + w1 * o1.y) * inv;
    o.z = (w0 * o0.z + w1 * o1.z) * inv;
    o.w = (w0 * o0.w + w1 * o1.w) * inv;
    *(float4*)(O + row * DD + c * 4) = o;
  }
}

extern "C" void kernel_launch(void* const* d_in, const int* in_sizes, int n_in,
                              void* d_out, int out_size, void* d_ws, size_t ws_size,
                              hipStream_t stream) {
  const float* Q = (const float*)d_in[0];
  const float* K = (const float*)d_in[1];
  const float* V = (const float*)d_in[2];
  float* Oo = (float*)d_out;

  const size_t rows = (size_t)BB * SS;                  // 65536
  const size_t need = (2 * rows * DD + 2 * rows * 2) * sizeof(float);  // ~33 MB
  if (ws_size >= need) {
    float* Op = (float*)d_ws;
    float* Ml = Op + 2 * rows * DD;
    hipLaunchKernelGGL((attn_fwd<16, true>), dim3(BB * NQB * 2), dim3(256), 0, stream,
                       Q, K, V, Oo, Op, Ml);
    hipLaunchKernelGGL(combine, dim3(rows / 64), dim3(256), 0, stream, Op, Ml, Oo);
  } else {
    hipLaunchKernelGGL((attn_fwd<32, false>), dim3(BB * NQB), dim3(256), 0, stream,
                       Q, K, V, Oo, (float*)nullptr, (float*)nullptr);
  }
}

// Round 15
// 65.500 us; speedup vs baseline: 2.2897x; 1.3714x over previous
//
#include <hip/hip_runtime.h>

typedef short    s16x8 __attribute__((ext_vector_type(8)));
typedef float    f32x4 __attribute__((ext_vector_type(4)));
typedef unsigned u32x4 __attribute__((ext_vector_type(4)));
typedef unsigned short ushort_t;

#define BB 32
#define SS 2048
#define DD 64
#define QBLK 64
#define KVBLK 64
#define NQB (SS / QBLK)          // 32
#define NTILES (SS / KVBLK)      // 32

#define QSCALE (0.125f * 1.44269504088896340736f)

#define V_OFF 8192
#define BUFSZ 16384

union U8 { u32x4 u; s16x8 s; };

__device__ __forceinline__ unsigned pk2bf(float lo, float hi) {
  unsigned r;
  asm("v_cvt_pk_bf16_f32 %0, %1, %2" : "=v"(r) : "v"(lo), "v"(hi));
  return r;
}

__device__ __forceinline__ void gll16(const void* g, void* l) {
  __builtin_amdgcn_global_load_lds(
      (const __attribute__((address_space(1))) void*)g,
      (__attribute__((address_space(3))) void*)l, 16, 0, 0);
}

// Drain staged vmem + own LDS reads, then sync (WAR-safe for next tile's gload_lds).
#define BARRIER() asm volatile("s_waitcnt vmcnt(0) lgkmcnt(0)\ns_barrier" ::: "memory")

// ---------------- prepass: K -> bf16 (QSCALE baked); V -> bf16, transposed with
// the PV k'-permutation baked into the global layout: Vt[b][d][t*64 + k'] where
// key(k'=c*8+j) = (c>>2)*32 + (j>>2)*16 + (c&3)*4 + (j&3).
__global__ __launch_bounds__(256, 8)
void prep(const float* __restrict__ K, const float* __restrict__ V,
          ushort_t* __restrict__ Kb, ushort_t* __restrict__ Vt) {
  __shared__ ushort_t tl[64 * 66];   // transpose tile, row stride 66 (bank-spread)
  const int bid = blockIdx.x, tid = threadIdx.x;
  if (bid < 2048) {
    const size_t base = (size_t)bid * 2048 + tid * 8;
    const float4 x = *(const float4*)(K + base);
    const float4 y = *(const float4*)(K + base + 4);
    u32x4 v = (u32x4){ pk2bf(x.x * QSCALE, x.y * QSCALE), pk2bf(x.z * QSCALE, x.w * QSCALE),
                       pk2bf(y.x * QSCALE, y.y * QSCALE), pk2bf(y.z * QSCALE, y.w * QSCALE) };
    *(u32x4*)(Kb + base) = v;
  } else {
    const int b2 = bid - 2048;           // 0..1023
    const int b = b2 >> 5, t = b2 & 31;
    const int r = tid >> 2, dq = tid & 3;   // key row, d-quarter
    // k' position of key r within the tile:
    const int kp = ((r >> 5) * 4 + ((r >> 2) & 3)) * 8 + ((r >> 4) & 1) * 4 + (r & 3);
    const float* src = V + ((size_t)b * SS + t * KVBLK + r) * DD + dq * 16;
    float f[16];
    *(float4*)(f + 0)  = *(const float4*)(src + 0);
    *(float4*)(f + 4)  = *(const float4*)(src + 4);
    *(float4*)(f + 8)  = *(const float4*)(src + 8);
    *(float4*)(f + 12) = *(const float4*)(src + 12);
#pragma unroll
    for (int j = 0; j < 16; ++j) {
      union { float fv; unsigned u; } cv; cv.fv = f[j];
      tl[(dq * 16 + j) * 66 + kp] = (ushort_t)((cv.u + 0x7FFF + ((cv.u >> 16) & 1)) >> 16);
    }
    __syncthreads();
    const int d = tid >> 2, ch = tid & 3;   // output row d, 2x16B chunks
    ushort_t* dst = Vt + ((size_t)b * DD + d) * SS + t * KVBLK + ch * 16;
#pragma unroll
    for (int h = 0; h < 2; ++h) {
      const unsigned* ls = (const unsigned*)(tl + d * 66 + ch * 16 + h * 8);
      u32x4 o = (u32x4){ ls[0], ls[1], ls[2], ls[3] };
      *(u32x4*)(dst + h * 8) = o;
    }
  }
}

// ---------------- main: r8-proven schedule, staging via global_load_lds ----------------
__global__ __launch_bounds__(256, 4)
void attn_fwd(const float* __restrict__ Q, const ushort_t* __restrict__ Kb,
              const ushort_t* __restrict__ Vt, float* __restrict__ O) {
  __shared__ __align__(16) char smem[2 * BUFSZ];
  const int tid  = threadIdx.x;
  const int w    = tid >> 6;
  const int lane = tid & 63;
  const int l15  = lane & 15;
  const int l16  = lane >> 4;

  // XCD-aware swizzle (bijective: 1024 = 8*128): 4 batches per XCD L2.
  const int bid0  = blockIdx.x;
  const int wid   = (bid0 & 7) * 128 + (bid0 >> 3);
  const int batch = wid >> 5;
  const int qb    = wid & 31;
  const size_t bstride = (size_t)batch * SS * DD;
  const int qrow0 = qb * QBLK + w * 16;

  // Q B-frags (scale baked into Kb)
  s16x8 aq[2];
#pragma unroll
  for (int dh = 0; dh < 2; ++dh) {
    const float* qp = Q + bstride + (size_t)(qrow0 + l15) * DD + dh * 32 + l16 * 8;
    const float4 x = *(const float4*)qp;
    const float4 y = *(const float4*)(qp + 4);
    U8 u;
    u.u = (u32x4){ pk2bf(x.x, x.y), pk2bf(x.z, x.w), pk2bf(y.x, y.y), pk2bf(y.z, y.w) };
    aq[dh] = u.s;
  }

  f32x4 oT[4];
#pragma unroll
  for (int dt = 0; dt < 4; ++dt) oT[dt] = (f32x4){0.f, 0.f, 0.f, 0.f};
  float mrun = -1e30f;
  float lsum = 0.f;

  // Staging geometry: wave w, instr i covers 16B slots s = w*128 + i*64 + lane
  // -> LDS row r = s>>3 (stride 128B), physical chunk cp = s&7 holding logical
  // chunk lc = cp ^ (r&7)  (inverse-swizzled SOURCE, linear DEST -- rule #21).
  const int s0  = w * 128 + lane;
  const int r0  = s0 >> 3;
  const int lc0 = (s0 & 7) ^ (r0 & 7);
  const ushort_t* gk0 = Kb + bstride + (size_t)r0 * DD + lc0 * 8;
  const ushort_t* gk1 = gk0 + 8 * DD;                       // rows r0+8: same lc
  const ushort_t* gv0 = Vt + (size_t)batch * DD * SS + (size_t)r0 * SS + lc0 * 8;
  const ushort_t* gv1 = gv0 + 8 * SS;
  char* lK = smem + w * 2048;          // wave-uniform LDS bases (+i*1024, +boff)
  char* lV = smem + V_OFF + w * 2048;

  auto ISSUE = [&](int t, int boff) {
    const size_t ko = (size_t)t * (KVBLK * DD);
    const size_t vo = (size_t)t * KVBLK;
    gll16(gk0 + ko, lK + boff);
    gll16(gk1 + ko, lK + boff + 1024);
    gll16(gv0 + vo, lV + boff);
    gll16(gv1 + vo, lV + boff + 1024);
  };

  auto compute = [&](int off) {
    s16x8 bk[4][2];
#pragma unroll
    for (int kc = 0; kc < 4; ++kc)
#pragma unroll
      for (int dh = 0; dh < 2; ++dh)
        bk[kc][dh] = *(const s16x8*)(smem + off + (kc * 16 + l15) * 128 +
                                     (((dh * 4 + l16) ^ (l15 & 7)) << 4));
    f32x4 s[4];
    __builtin_amdgcn_s_setprio(1);
#pragma unroll
    for (int kc = 0; kc < 4; ++kc) {
      s[kc] = (f32x4){0.f, 0.f, 0.f, 0.f};
      s[kc] = __builtin_amdgcn_mfma_f32_16x16x32_bf16(bk[kc][0], aq[0], s[kc], 0, 0, 0);
      s[kc] = __builtin_amdgcn_mfma_f32_16x16x32_bf16(bk[kc][1], aq[1], s[kc], 0, 0, 0);
    }
    __builtin_amdgcn_s_setprio(0);

    float m01 = fmaxf(fmaxf(fmaxf(s[0][0], s[0][1]), fmaxf(s[0][2], s[0][3])),
                      fmaxf(fmaxf(s[1][0], s[1][1]), fmaxf(s[1][2], s[1][3])));
    float m23 = fmaxf(fmaxf(fmaxf(s[2][0], s[2][1]), fmaxf(s[2][2], s[2][3])),
                      fmaxf(fmaxf(s[3][0], s[3][1]), fmaxf(s[3][2], s[3][3])));
    float mx = fmaxf(m01, m23);
    mx = fmaxf(mx, __shfl_xor(mx, 16));
    mx = fmaxf(mx, __shfl_xor(mx, 32));
    const int skip = __all(mx <= mrun + 8.0f);
    if (!skip) {
      const float mnew = fmaxf(mrun, mx);
      const float scl  = __builtin_amdgcn_exp2f(mrun - mnew);
      lsum *= scl;
#pragma unroll
      for (int dt = 0; dt < 4; ++dt) oT[dt] = oT[dt] * scl;
      mrun = mnew;
    }
    s16x8 vt[4][2];
#pragma unroll
    for (int dt = 0; dt < 4; ++dt)
#pragma unroll
      for (int kc2 = 0; kc2 < 2; ++kc2)
        vt[dt][kc2] = *(const s16x8*)(smem + off + V_OFF + (dt * 16 + l15) * 128 +
                                      (((kc2 * 4 + l16) ^ (l15 & 7)) << 4));
    float p[4][4];
#pragma unroll
    for (int kc = 0; kc < 4; ++kc)
#pragma unroll
      for (int r = 0; r < 4; ++r)
        p[kc][r] = __builtin_amdgcn_exp2f(s[kc][r] - mrun);
    lsum += ((((p[0][0] + p[0][1]) + (p[0][2] + p[0][3])) +
              ((p[1][0] + p[1][1]) + (p[1][2] + p[1][3]))) +
             (((p[2][0] + p[2][1]) + (p[2][2] + p[2][3])) +
              ((p[3][0] + p[3][1]) + (p[3][2] + p[3][3]))));
    U8 pb0, pb1;
    pb0.u = (u32x4){ pk2bf(p[0][0], p[0][1]), pk2bf(p[0][2], p[0][3]),
                     pk2bf(p[1][0], p[1][1]), pk2bf(p[1][2], p[1][3]) };
    pb1.u = (u32x4){ pk2bf(p[2][0], p[2][1]), pk2bf(p[2][2], p[2][3]),
                     pk2bf(p[3][0], p[3][1]), pk2bf(p[3][2], p[3][3]) };
    __builtin_amdgcn_s_setprio(1);
#pragma unroll
    for (int dt = 0; dt < 4; ++dt) {
      oT[dt] = __builtin_amdgcn_mfma_f32_16x16x32_bf16(vt[dt][0], pb0.s, oT[dt], 0, 0, 0);
      oT[dt] = __builtin_amdgcn_mfma_f32_16x16x32_bf16(vt[dt][1], pb1.s, oT[dt], 0, 0, 0);
    }
    __builtin_amdgcn_s_setprio(0);
  };

  // prologue
  ISSUE(0, 0);
  asm volatile("s_waitcnt vmcnt(0)" ::: "memory");
  __builtin_amdgcn_s_barrier();
  // main loop: issue t+1 (flies during compute t), 1 barrier/tile
  for (int i = 0; i < NTILES / 2 - 1; ++i) {
    ISSUE(2 * i + 1, BUFSZ); compute(0);     BARRIER();
    ISSUE(2 * i + 2, 0);     compute(BUFSZ); BARRIER();
  }
  ISSUE(NTILES - 1, BUFSZ);
  compute(0);
  BARRIER();
  compute(BUFSZ);

  // epilogue
  float lr = lsum;
  lr += __shfl_xor(lr, 16);
  lr += __shfl_xor(lr, 32);
  const float inv = 1.0f / lr;
  float* ob = O + bstride + (size_t)(qrow0 + l15) * DD + l16 * 4;
#pragma unroll
  for (int dt = 0; dt < 4; ++dt)
#pragma unroll
    for (int r = 0; r < 4; ++r)
      ob[dt * 16 + r] = oT[dt][r] * inv;
}

extern "C" void kernel_launch(void* const* d_in, const int* in_sizes, int n_in,
                              void* d_out, int out_size, void* d_ws, size_t ws_size,
                              hipStream_t stream) {
  const float* Q = (const float*)d_in[0];
  const float* K = (const float*)d_in[1];
  const float* V = (const float*)d_in[2];
  float* Oo = (float*)d_out;

  const size_t elems = (size_t)BB * SS * DD;            // 4,194,304
  const size_t need  = 2 * elems * sizeof(ushort_t);    // 16 MB (ws >= 33 MB, proven r14)
  if (ws_size < need) return;                           // loud failure if assumption breaks
  ushort_t* Kb = (ushort_t*)d_ws;
  ushort_t* Vt = Kb + elems;

  hipLaunchKernelGGL(prep, dim3(3072), dim3(256), 0, stream, K, V, Kb, Vt);
  hipLaunchKernelGGL(attn_fwd, dim3(BB * NQB), dim3(256), 0, stream, Q, Kb, Vt, Oo);
}